// Round 6
// baseline (659.401 us; speedup 1.0000x reference)
//
#include <hip/hip_runtime.h>
#include <math.h>

#define NA 100000
#define NB 100000
#define KDIM 256
#define ODIM 256
#define NEDGE 320000
#define CAP 32              // per-bucket capacity; deg ~ Poisson(3.2), P(>=32) ~ 1e-20
#define NBUCK (2 * NA)      // path-major destination buckets

typedef unsigned int u32;
typedef _Float16 f16x8 __attribute__((ext_vector_type(8)));
typedef float    f32x4 __attribute__((ext_vector_type(4)));

// ---------------------------------------------------------------------------
// W -> transposed f16: Wth[n][k], n in [0,512) = [W0^T; W1^T], plus biases.
// ---------------------------------------------------------------------------
__global__ __launch_bounds__(256) void convert_w(
    const float* __restrict__ W0, const float* __restrict__ b0,
    const float* __restrict__ W1, const float* __restrict__ b1,
    _Float16* __restrict__ Wth, float* __restrict__ bcat)
{
    const int t = blockIdx.x * 256 + threadIdx.x;      // 512*32 threads
    if (t >= 512 * 32) return;
    const int n  = t >> 5;
    const int kb = (t & 31) * 8;
    const float* src = (n < ODIM) ? (W0 + n) : (W1 + (n - ODIM));
    f16x8 vh;
    #pragma unroll
    for (int j = 0; j < 8; ++j)
        vh[j] = (_Float16)src[(size_t)(kb + j) * ODIM];
    *(f16x8*)&Wth[(size_t)n * KDIM + kb] = vh;
    if ((t & 31) == 0) bcat[n] = (n < ODIM) ? b0[n] : b1[n - ODIM];
}

// ---------------------------------------------------------------------------
// x_B f32 -> f16: halves the random-gather row to 512 B; source L3-resident.
// ---------------------------------------------------------------------------
__global__ __launch_bounds__(256) void convert_x(
    const float* __restrict__ x, _Float16* __restrict__ xh)
{
    const size_t c = ((size_t)blockIdx.x * 256 + threadIdx.x) * 8;  // exact cover
    const float4* p = (const float4*)&x[c];
    float4 a = p[0], b = p[1];
    f16x8 v;
    v[0] = (_Float16)a.x; v[1] = (_Float16)a.y;
    v[2] = (_Float16)a.z; v[3] = (_Float16)a.w;
    v[4] = (_Float16)b.x; v[5] = (_Float16)b.y;
    v[6] = (_Float16)b.z; v[7] = (_Float16)b.w;
    *(f16x8*)&xh[c] = v;
}

// ---------------------------------------------------------------------------
// Bucketed adjacency: fixed CAP slots per (path,dst). One pass, no scans.
// ---------------------------------------------------------------------------
__global__ __launch_bounds__(256) void bucket_fill(
    const int* __restrict__ ei0, const int* __restrict__ ei1,
    u32* __restrict__ cnt, int* __restrict__ elist)
{
    const int gid = blockIdx.x * 256 + threadIdx.x;
    if (gid >= 2 * NEDGE) return;
    const int p = (gid >= NEDGE) ? 1 : 0;
    const int j = gid - p * NEDGE;
    const int* ei = p ? ei1 : ei0;
    const int src = ei[j];
    const int dst = ei[NEDGE + j];
    const u32 b = (u32)(p * NA + dst);
    const u32 pos = atomicAdd(&cnt[b], 1u);
    if (pos < CAP) elist[(size_t)b * CAP + pos] = src;
}

// ---------------------------------------------------------------------------
// Gather-mean of f16 x rows (projection commutes with the mean).
// One wave per dst: lanes 0-31 path0, 32-63 path1, 8 cols (16 B) per lane.
// ---------------------------------------------------------------------------
__global__ __launch_bounds__(256) void agg_mean(
    const _Float16* __restrict__ xh, const u32* __restrict__ cnt,
    const int* __restrict__ elist, _Float16* __restrict__ aggx)
{
    const int row  = (int)((blockIdx.x * (size_t)blockDim.x + threadIdx.x) >> 6);
    const int lane = threadIdx.x & 63;
    if (row >= NA) return;
    const int p  = lane >> 5;
    const int li = lane & 31;
    const int c  = li * 8;

    const u32 b  = (u32)(p * NA + row);
    const u32 nt = cnt[b];
    const u32 n  = min(nt, (u32)CAP);
    const int* el = &elist[(size_t)b * CAP];

    float a[8] = {};
    for (u32 j = 0; j < n; ++j) {
        const int src = el[j];
        const f16x8 v = *(const f16x8*)&xh[(size_t)src * KDIM + c];
        #pragma unroll
        for (int i = 0; i < 8; ++i) a[i] += (float)v[i];
    }
    const float inv = 1.0f / fmaxf((float)nt, 1.0f);
    f16x8 o;
    #pragma unroll
    for (int i = 0; i < 8; ++i) o[i] = (_Float16)(a[i] * inv);
    *(f16x8*)&aggx[((size_t)p * NA + row) * KDIM + c] = o;
}

// ---------------------------------------------------------------------------
// Fused GEMM + finalize.  Block = 64 dst rows; 4 waves = (path p, col-half).
//   GEMM: proj[p] = aggx[p] @ W_p + b_p for 64 rows x 512 cols, A staged via
//         the proven slot scheme (path-major offset), B direct from L2-hot Wth
//         (fragment bytes identical to the proven staged slots).
//   proj -> LDS P[64][520] f16 (separate buffer, one barrier), then the
//   proven finalize math: wave w finalizes rows w*16..w*16+15.
//   Also zeroes its 64 out_B rows (overlaps staging) -> no memset, no pagg.
// ---------------------------------------------------------------------------
__global__ __launch_bounds__(256) void gemm_finalize(
    const _Float16* __restrict__ aggx, const _Float16* __restrict__ Wth,
    const float* __restrict__ bcat, const u32* __restrict__ cnt,
    const float* __restrict__ sem, const float* __restrict__ gamma,
    const float* __restrict__ beta, float* __restrict__ out)
{
    __shared__ __align__(16) f16x8 Ah[512];            // 8 KB A staging
    __shared__ __align__(16) _Float16 P[64][520];      // 66.6 KB proj (no alias)

    const int t    = threadIdx.x;
    const int w    = t >> 6;
    const int lane = t & 63;
    const int m0   = blockIdx.x * 64;
    const int p    = w >> 1;                 // wave's path
    const int n0w  = (w & 1) * 128;          // wave's col half (within path)
    const int r16  = lane & 15;
    const int kc   = (lane >> 4) * 8;
    const int srow = w * 16 + r16;           // staging row 0..63

    // ---- zero this block's out_B rows (overlaps with staging latency) ----
    {
        float* outB = out + (size_t)NA * ODIM;
        f32x4 z = {};
        #pragma unroll
        for (int it = 0; it < 16; ++it) {
            const int idx = it * 256 + t;    // f32x4 index in 64-row band
            const int r = idx >> 6;          // 64 f32x4 per row
            if (m0 + r < NA)
                *(f32x4*)&outB[(size_t)(m0 + r) * ODIM + (idx & 63) * 4] = z;
        }
    }

    const int arow  = min(m0 + srow, NA - 1);
    const size_t a0off = (size_t)arow * KDIM + kc;            // path0
    const size_t a1off = ((size_t)NA + arow) * KDIM + kc;     // path1

    int boff[8];
    #pragma unroll
    for (int j = 0; j < 8; ++j)
        boff[j] = (p * 256 + n0w + j * 16 + r16) * KDIM + kc;

    f32x4 acc[4][8] = {};

    for (int k0 = 0; k0 < KDIM; k0 += 32) {
        const f16x8 ga0 = *(const f16x8*)&aggx[a0off + k0];
        const f16x8 ga1 = *(const f16x8*)&aggx[a1off + k0];
        __syncthreads();                 // previous iter's frag reads done
        Ah[t] = ga0;  Ah[t + 256] = ga1; // slot = p*256 + m16*64 + lane
        __syncthreads();

        f16x8 af[4];
        #pragma unroll
        for (int i = 0; i < 4; ++i) af[i] = Ah[p * 256 + i * 64 + lane];
        #pragma unroll
        for (int j = 0; j < 8; ++j) {
            const f16x8 bh = *(const f16x8*)&Wth[boff[j] + k0];
            #pragma unroll
            for (int i = 0; i < 4; ++i)
                acc[i][j] = __builtin_amdgcn_mfma_f32_16x16x32_f16(
                    af[i], bh, acc[i][j], 0, 0, 0);
        }
    }

    // ---- biased proj -> P (f16).  C-frag: row = quad*4+e, col = j*16+c16 ----
    const int quad = lane >> 4, c16 = lane & 15;
    float bias[8];
    #pragma unroll
    for (int j = 0; j < 8; ++j)
        bias[j] = bcat[p * 256 + n0w + j * 16 + c16];
    #pragma unroll
    for (int i = 0; i < 4; ++i)
        #pragma unroll
        for (int j = 0; j < 8; ++j)
            #pragma unroll
            for (int e = 0; e < 4; ++e)
                P[i * 16 + quad * 4 + e][p * 256 + n0w + j * 16 + c16] =
                    (_Float16)(acc[i][j][e] + bias[j]);
    __syncthreads();                     // all P writes visible

    // ---- finalize (proven math): wave w owns rows w*16..w*16+15 ----------
    const int fp = lane >> 5;            // finalize path
    const int li = lane & 31;
    const int c  = li * 8;

    for (int rr = 0; rr < 16; ++rr) {
        const int r  = w * 16 + rr;
        const int rg = m0 + r;
        if (rg >= NA) break;             // wave-uniform

        const u32 n = cnt[fp * NA + rg];
        const f16x8 v = *(const f16x8*)&P[r][fp * 256 + c];
        float m[8];
        #pragma unroll
        for (int i = 0; i < 8; ++i) m[i] = (n > 0) ? (float)v[i] : 0.0f;

        // semantic score for own path
        float4 s0 = *(const float4*)&sem[c];
        float4 s1 = *(const float4*)&sem[c + 4];
        float sv[8] = {s0.x, s0.y, s0.z, s0.w, s1.x, s1.y, s1.z, s1.w};
        float s = 0.f;
        #pragma unroll
        for (int i = 0; i < 8; ++i) s += tanhf(m[i]) * sv[i];
        #pragma unroll
        for (int off = 1; off <= 16; off <<= 1) s += __shfl_xor(s, off);
        const float so = __shfl_xor(s, 32);
        const float mx = fmaxf(s, so);
        const float e  = __expf(s - mx), eo = __expf(so - mx);
        const float wown = e / (e + eo), woth = eo / (e + eo);

        float fused[8];
        float sum = 0.f, sq = 0.f;
        #pragma unroll
        for (int i = 0; i < 8; ++i) {
            const float mo = __shfl_xor(m[i], 32);
            float f = fmaxf(wown * m[i] + woth * mo, 0.f);
            fused[i] = f;
            sum += f;
            sq  += f * f;
        }
        #pragma unroll
        for (int off = 1; off <= 32; off <<= 1) {
            sum += __shfl_xor(sum, off);
            sq  += __shfl_xor(sq,  off);
        }
        // both halves hold duplicates -> totals are 2x
        const float mu  = sum * (0.5f / ODIM);
        const float var = sq  * (0.5f / ODIM) - mu * mu;
        const float rinv = rsqrtf(var + 1e-5f);

        if (fp == 0) {
            float4 g0 = *(const float4*)&gamma[c];
            float4 g1 = *(const float4*)&gamma[c + 4];
            float4 b0 = *(const float4*)&beta[c];
            float4 b1 = *(const float4*)&beta[c + 4];
            float gv[8] = {g0.x, g0.y, g0.z, g0.w, g1.x, g1.y, g1.z, g1.w};
            float bv[8] = {b0.x, b0.y, b0.z, b0.w, b1.x, b1.y, b1.z, b1.w};
            float o[8];
            #pragma unroll
            for (int i = 0; i < 8; ++i)
                o[i] = (fused[i] - mu) * rinv * gv[i] + bv[i];
            float4 o0, o1;
            o0.x = o[0]; o0.y = o[1]; o0.z = o[2]; o0.w = o[3];
            o1.x = o[4]; o1.y = o[5]; o1.z = o[6]; o1.w = o[7];
            *(float4*)&out[(size_t)rg * ODIM + c]     = o0;
            *(float4*)&out[(size_t)rg * ODIM + c + 4] = o1;
        }
    }
}

// ---------------------------------------------------------------------------
extern "C" void kernel_launch(void* const* d_in, const int* in_sizes, int n_in,
                              void* d_out, int out_size, void* d_ws, size_t ws_size,
                              hipStream_t stream)
{
    const float* xB   = (const float*)d_in[1];
    const int*   ei0  = (const int*)d_in[2];
    const int*   ei1  = (const int*)d_in[3];
    const float* W0   = (const float*)d_in[4];
    const float* b0   = (const float*)d_in[5];
    const float* W1   = (const float*)d_in[6];
    const float* b1   = (const float*)d_in[7];
    const float* sem  = (const float*)d_in[8];
    const float* gam  = (const float*)d_in[9];
    const float* bet  = (const float*)d_in[10];

    float* out = (float*)d_out;

    // workspace (~180 MB): xh + aggx + cnt + elist + Wt + biases
    _Float16* xh   = (_Float16*)d_ws;                          // 51.2 MB
    _Float16* aggx = xh + (size_t)NB * KDIM;                   // 102.4 MB
    u32* cnt   = (u32*)(aggx + (size_t)2 * NA * KDIM);         // 0.8 MB
    int* elist = (int*)(cnt + NBUCK);                          // 25.6 MB
    _Float16* Wth = (_Float16*)(elist + (size_t)NBUCK * CAP);  // 0.25 MB
    float*    bcat = (float*)(Wth + (size_t)512 * KDIM);       // 2 KB

    // 1) W -> transposed f16 + biases (tiny)
    convert_w<<<64, 256, 0, stream>>>(W0, b0, W1, b1, Wth, bcat);

    // 2) x_B -> f16 (gather source becomes L3-resident)
    convert_x<<<(NB * KDIM / 8) / 256, 256, 0, stream>>>(xB, xh);

    // 3) bucketed adjacency (one atomic pass, no scans)
    hipMemsetAsync(cnt, 0, (size_t)NBUCK * sizeof(u32), stream);
    bucket_fill<<<(2 * NEDGE + 255) / 256, 256, 0, stream>>>(ei0, ei1, cnt, elist);

    // 4) gather-mean of f16 x rows (projection commutes with mean)
    agg_mean<<<(NA + 3) / 4, 256, 0, stream>>>(xh, cnt, elist, aggx);

    // 5) fused GEMM + semantic softmax + LN -> out_A; zeroes out_B in-kernel
    gemm_finalize<<<(NA + 63) / 64, 256, 0, stream>>>(aggx, Wth, bcat, cnt,
                                                      sem, gam, bet, out);
}

// Round 7
// 628.629 us; speedup vs baseline: 1.0490x; 1.0490x over previous
//
#include <hip/hip_runtime.h>
#include <math.h>

#define NA 100000
#define NB 100000
#define KDIM 256
#define ODIM 256
#define NEDGE 320000
#define CAP 32              // per-bucket capacity; deg ~ Poisson(3.2), P(>=32) ~ 1e-20
#define NBUCK (2 * NA)      // path-major destination buckets

typedef unsigned int u32;
typedef _Float16 f16x8 __attribute__((ext_vector_type(8)));
typedef float    f32x4 __attribute__((ext_vector_type(4)));

// ---------------------------------------------------------------------------
// Prep (one dispatch): W -> transposed f16 Wth[n][k] (n<512 = [W0^T;W1^T]) +
// biases; x_B f32 -> f16; zero cnt.  Grid covers x conversion (3.2M threads).
// ---------------------------------------------------------------------------
__global__ __launch_bounds__(256) void prep(
    const float* __restrict__ W0, const float* __restrict__ b0,
    const float* __restrict__ W1, const float* __restrict__ b1,
    const float* __restrict__ x,
    _Float16* __restrict__ Wth, float* __restrict__ bcat,
    _Float16* __restrict__ xh, u32* __restrict__ cnt)
{
    const int gid = blockIdx.x * 256 + threadIdx.x;

    // zero adjacency counters (before bucket_fill dispatch)
    if (gid < NBUCK) cnt[gid] = 0u;

    // W -> f16 transposed (16384 threads)
    if (gid < 512 * 32) {
        const int n  = gid >> 5;
        const int kb = (gid & 31) * 8;
        const float* src = (n < ODIM) ? (W0 + n) : (W1 + (n - ODIM));
        f16x8 vh;
        #pragma unroll
        for (int j = 0; j < 8; ++j)
            vh[j] = (_Float16)src[(size_t)(kb + j) * ODIM];
        *(f16x8*)&Wth[(size_t)n * KDIM + kb] = vh;
        if ((gid & 31) == 0) bcat[n] = (n < ODIM) ? b0[n] : b1[n - ODIM];
    }

    // x -> f16 (exact cover: grid sized for this)
    const size_t c = (size_t)gid * 8;
    if (c < (size_t)NB * KDIM) {
        const float4* p = (const float4*)&x[c];
        float4 a = p[0], b = p[1];
        f16x8 v;
        v[0] = (_Float16)a.x; v[1] = (_Float16)a.y;
        v[2] = (_Float16)a.z; v[3] = (_Float16)a.w;
        v[4] = (_Float16)b.x; v[5] = (_Float16)b.y;
        v[6] = (_Float16)b.z; v[7] = (_Float16)b.w;
        *(f16x8*)&xh[c] = v;
    }
}

// ---------------------------------------------------------------------------
// Bucketed adjacency: fixed CAP slots per (path,dst). One pass, no scans.
// ---------------------------------------------------------------------------
__global__ __launch_bounds__(256) void bucket_fill(
    const int* __restrict__ ei0, const int* __restrict__ ei1,
    u32* __restrict__ cnt, int* __restrict__ elist)
{
    const int gid = blockIdx.x * 256 + threadIdx.x;
    if (gid >= 2 * NEDGE) return;
    const int p = (gid >= NEDGE) ? 1 : 0;
    const int j = gid - p * NEDGE;
    const int* ei = p ? ei1 : ei0;
    const int src = ei[j];
    const int dst = ei[NEDGE + j];
    const u32 b = (u32)(p * NA + dst);
    const u32 pos = atomicAdd(&cnt[b], 1u);
    if (pos < CAP) elist[(size_t)b * CAP + pos] = src;
}

// ---------------------------------------------------------------------------
// Gather-mean of f16 x rows (projection commutes with the mean).
// One wave per dst: lanes 0-31 path0, 32-63 path1, 8 cols (16 B) per lane.
// ---------------------------------------------------------------------------
__global__ __launch_bounds__(256) void agg_mean(
    const _Float16* __restrict__ xh, const u32* __restrict__ cnt,
    const int* __restrict__ elist, _Float16* __restrict__ aggx)
{
    const int row  = (int)((blockIdx.x * (size_t)blockDim.x + threadIdx.x) >> 6);
    const int lane = threadIdx.x & 63;
    if (row >= NA) return;
    const int p  = lane >> 5;
    const int li = lane & 31;
    const int c  = li * 8;

    const u32 b  = (u32)(p * NA + row);
    const u32 nt = cnt[b];
    const u32 n  = min(nt, (u32)CAP);
    const int* el = &elist[(size_t)b * CAP];

    float a[8] = {};
    for (u32 j = 0; j < n; ++j) {
        const int src = el[j];
        const f16x8 v = *(const f16x8*)&xh[(size_t)src * KDIM + c];
        #pragma unroll
        for (int i = 0; i < 8; ++i) a[i] += (float)v[i];
    }
    const float inv = 1.0f / fmaxf((float)nt, 1.0f);
    f16x8 o;
    #pragma unroll
    for (int i = 0; i < 8; ++i) o[i] = (_Float16)(a[i] * inv);
    *(f16x8*)&aggx[((size_t)p * NA + row) * KDIM + c] = o;
}

// ---------------------------------------------------------------------------
// f16 MFMA GEMM: pagg = f16( aggx @ W_p + b_p ).  128x256 tile, one block per
// (path, m-tile): grid 1564.  A staged via the proven LDS slot scheme; B read
// DIRECT from L2-hot Wth (fragment bytes == proven staged slots, verified R6).
// 4 waves = 2x2 over (m-half, n-half-of-256); acc[4][8]; 32 MFMA/wave/K-step.
// Epilogue = proven per-wave [16][68] f32 roundtrip, run twice (n-halves).
// ---------------------------------------------------------------------------
__global__ __launch_bounds__(256) void proj_gemm(
    const _Float16* __restrict__ aggx, const _Float16* __restrict__ Wth,
    const float* __restrict__ bcat, _Float16* __restrict__ pagg)
{
    __shared__ __align__(16) char smem[17408];
    f16x8* Ah = (f16x8*)smem;               // 512 slots (8 KB), A staging only

    const int t    = threadIdx.x;
    const int w    = t >> 6;
    const int lane = t & 63;
    const int p    = (blockIdx.x >= 782) ? 1 : 0;
    const int m0   = (blockIdx.x - p * 782) * 128;
    const int wm   = w & 1, wn = w >> 1;     // wn = n-half of 256 (cols wn*128)
    const int r16  = lane & 15;
    const int kc   = (lane >> 4) * 8;
    const int srow = w * 16 + r16;           // staging row 0..63

    const int arow0 = min(m0 + srow,      NA - 1);
    const int arow1 = min(m0 + srow + 64, NA - 1);
    const _Float16* Ap = aggx + (size_t)p * NA * KDIM;

    int boff[8];
    #pragma unroll
    for (int j = 0; j < 8; ++j)
        boff[j] = (p * 256 + wn * 128 + j * 16 + r16) * KDIM + kc;

    f32x4 acc[4][8] = {};

    for (int k0 = 0; k0 < KDIM; k0 += 32) {
        const f16x8 ga0 = *(const f16x8*)&Ap[(size_t)arow0 * KDIM + k0 + kc];
        const f16x8 ga1 = *(const f16x8*)&Ap[(size_t)arow1 * KDIM + k0 + kc];
        __syncthreads();                 // previous iter's af reads done
        Ah[t] = ga0;  Ah[t + 256] = ga1; // slot = m16*64 + lane (rows 0..127)
        __syncthreads();

        f16x8 af[4];
        #pragma unroll
        for (int i = 0; i < 4; ++i) af[i] = Ah[(wm * 4 + i) * 64 + lane];
        #pragma unroll
        for (int j = 0; j < 8; ++j) {
            const f16x8 bh = *(const f16x8*)&Wth[boff[j] + k0];
            #pragma unroll
            for (int i = 0; i < 4; ++i)
                acc[i][j] = __builtin_amdgcn_mfma_f32_16x16x32_f16(
                    af[i], bh, acc[i][j], 0, 0, 0);
        }
    }

    float bias[8];
    #pragma unroll
    for (int j = 0; j < 8; ++j)
        bias[j] = bcat[p * 256 + wn * 128 + j * 16 + r16];

    // epilogue: proven per-wave [16][68] f32 roundtrip, two n-half passes.
    const int quad = lane >> 4, c16 = lane & 15;
    const int lr = lane >> 2, lc = (lane & 3) * 16;

    for (int i = 0; i < 4; ++i) {        // mt band
        #pragma unroll
        for (int jh = 0; jh < 2; ++jh) { // n-half band
            __syncthreads();             // staging/ep reads done (WAR)
            float* ep = (float*)(smem + w * 4352);
            #pragma unroll
            for (int jj = 0; jj < 4; ++jj) {
                const int j = jh * 4 + jj;
                #pragma unroll
                for (int r = 0; r < 4; ++r)
                    ep[(quad * 4 + r) * 68 + jj * 16 + c16] =
                        acc[i][j][r] + bias[j];
            }
            __syncthreads();
            f32x4 v0 = *(f32x4*)&ep[lr * 68 + lc + 0];
            f32x4 v1 = *(f32x4*)&ep[lr * 68 + lc + 4];
            f32x4 v2 = *(f32x4*)&ep[lr * 68 + lc + 8];
            f32x4 v3 = *(f32x4*)&ep[lr * 68 + lc + 12];
            const int rg = m0 + wm * 64 + i * 16 + lr;
            if (rg < NA) {
                f16x8 o0, o1;
                o0[0] = (_Float16)v0[0]; o0[1] = (_Float16)v0[1];
                o0[2] = (_Float16)v0[2]; o0[3] = (_Float16)v0[3];
                o0[4] = (_Float16)v1[0]; o0[5] = (_Float16)v1[1];
                o0[6] = (_Float16)v1[2]; o0[7] = (_Float16)v1[3];
                o1[0] = (_Float16)v2[0]; o1[1] = (_Float16)v2[1];
                o1[2] = (_Float16)v2[2]; o1[3] = (_Float16)v2[3];
                o1[4] = (_Float16)v3[0]; o1[5] = (_Float16)v3[1];
                o1[6] = (_Float16)v3[2]; o1[7] = (_Float16)v3[3];
                _Float16* dst = &pagg[((size_t)p * NA + rg) * ODIM
                                      + wn * 128 + jh * 64 + lc];
                *(f16x8*)(dst + 0) = o0;
                *(f16x8*)(dst + 8) = o1;
            }
        }
    }
}

// ---------------------------------------------------------------------------
// Streaming finalize: read pagg rows (contiguous), mask cnt==0, then
// tanh/sem scores -> 2-way softmax -> fuse -> relu -> LayerNorm -> out_A.
// Each wave ZEROES the exact pagg chunk it read afterwards (exact cover of
// the out_B half, race-free) so no separate out_B memset is needed.
// ---------------------------------------------------------------------------
__global__ __launch_bounds__(256) void finalize(
    _Float16* __restrict__ pagg, const u32* __restrict__ cnt,
    float* __restrict__ out,
    const float* __restrict__ sem, const float* __restrict__ gamma,
    const float* __restrict__ beta)
{
    const int row  = (int)((blockIdx.x * (size_t)blockDim.x + threadIdx.x) >> 6);
    const int lane = threadIdx.x & 63;
    if (row >= NA) return;
    const int p  = lane >> 5;
    const int li = lane & 31;
    const int c  = li * 8;

    const u32 n = cnt[p * NA + row];
    _Float16* pp = &pagg[((size_t)p * NA + row) * ODIM + c];
    const f16x8 v = *(const f16x8*)pp;
    float m[8];
    #pragma unroll
    for (int i = 0; i < 8; ++i) m[i] = (n > 0) ? (float)v[i] : 0.0f;

    // zero out_B (this lane's exact chunk) — replaces the 102.4 MB memset
    f16x8 z = {};
    *(f16x8*)pp = z;

    // semantic score for own path
    float4 s0 = *(const float4*)&sem[c];
    float4 s1 = *(const float4*)&sem[c + 4];
    float sv[8] = {s0.x, s0.y, s0.z, s0.w, s1.x, s1.y, s1.z, s1.w};
    float s = 0.f;
    #pragma unroll
    for (int i = 0; i < 8; ++i) s += tanhf(m[i]) * sv[i];
    #pragma unroll
    for (int off = 1; off <= 16; off <<= 1) s += __shfl_xor(s, off);
    const float so = __shfl_xor(s, 32);
    const float mx = fmaxf(s, so);
    const float e  = __expf(s - mx), eo = __expf(so - mx);
    const float wown = e / (e + eo), woth = eo / (e + eo);

    float fused[8];
    float sum = 0.f, sq = 0.f;
    #pragma unroll
    for (int i = 0; i < 8; ++i) {
        const float mo = __shfl_xor(m[i], 32);
        float f = fmaxf(wown * m[i] + woth * mo, 0.f);
        fused[i] = f;
        sum += f;
        sq  += f * f;
    }
    #pragma unroll
    for (int off = 1; off <= 32; off <<= 1) {
        sum += __shfl_xor(sum, off);
        sq  += __shfl_xor(sq,  off);
    }
    // both halves hold duplicates -> totals are 2x
    const float mu  = sum * (0.5f / ODIM);
    const float var = sq  * (0.5f / ODIM) - mu * mu;
    const float rinv = rsqrtf(var + 1e-5f);

    if (p == 0) {
        float4 g0 = *(const float4*)&gamma[c];
        float4 g1 = *(const float4*)&gamma[c + 4];
        float4 b0 = *(const float4*)&beta[c];
        float4 b1 = *(const float4*)&beta[c + 4];
        float gv[8] = {g0.x, g0.y, g0.z, g0.w, g1.x, g1.y, g1.z, g1.w};
        float bv[8] = {b0.x, b0.y, b0.z, b0.w, b1.x, b1.y, b1.z, b1.w};
        float o[8];
        #pragma unroll
        for (int i = 0; i < 8; ++i) o[i] = (fused[i] - mu) * rinv * gv[i] + bv[i];
        float4 o0, o1;
        o0.x = o[0]; o0.y = o[1]; o0.z = o[2]; o0.w = o[3];
        o1.x = o[4]; o1.y = o[5]; o1.z = o[6]; o1.w = o[7];
        *(float4*)&out[(size_t)row * ODIM + c]     = o0;
        *(float4*)&out[(size_t)row * ODIM + c + 4] = o1;
    }
}

// ---------------------------------------------------------------------------
extern "C" void kernel_launch(void* const* d_in, const int* in_sizes, int n_in,
                              void* d_out, int out_size, void* d_ws, size_t ws_size,
                              hipStream_t stream)
{
    const float* xB   = (const float*)d_in[1];
    const int*   ei0  = (const int*)d_in[2];
    const int*   ei1  = (const int*)d_in[3];
    const float* W0   = (const float*)d_in[4];
    const float* b0   = (const float*)d_in[5];
    const float* W1   = (const float*)d_in[6];
    const float* b1   = (const float*)d_in[7];
    const float* sem  = (const float*)d_in[8];
    const float* gam  = (const float*)d_in[9];
    const float* bet  = (const float*)d_in[10];

    float* out = (float*)d_out;

    // workspace (~180 MB): xh + aggx + cnt + elist + Wt + biases
    _Float16* xh   = (_Float16*)d_ws;                          // 51.2 MB
    _Float16* aggx = xh + (size_t)NB * KDIM;                   // 102.4 MB
    u32* cnt   = (u32*)(aggx + (size_t)2 * NA * KDIM);         // 0.8 MB
    int* elist = (int*)(cnt + NBUCK);                          // 25.6 MB
    _Float16* Wth = (_Float16*)(elist + (size_t)NBUCK * CAP);  // 0.25 MB
    float*    bcat = (float*)(Wth + (size_t)512 * KDIM);       // 2 KB

    // pagg (f16, 102.4 MB) lives in the out_B half of d_out; finalize zeroes it.
    _Float16* pagg = (_Float16*)(out + (size_t)NA * ODIM);

    // 1) prep: W->f16^T + biases, x->f16, zero cnt   (one dispatch)
    prep<<<(NB * KDIM / 8) / 256, 256, 0, stream>>>(W0, b0, W1, b1, xB,
                                                    Wth, bcat, xh, cnt);

    // 2) bucketed adjacency (one atomic pass, no scans)
    bucket_fill<<<(2 * NEDGE + 255) / 256, 256, 0, stream>>>(ei0, ei1, cnt, elist);

    // 3) gather-mean of f16 x rows (projection commutes with mean)
    agg_mean<<<(NA + 3) / 4, 256, 0, stream>>>(xh, cnt, elist, aggx);

    // 4) f16 MFMA GEMM on aggregates -> pagg (128x256 tile, B direct from L2)
    proj_gemm<<<1564, 256, 0, stream>>>(aggx, Wth, bcat, pagg);

    // 5) streaming finalize -> out_A; self-zeroes pagg (= out_B half)
    finalize<<<(NA + 3) / 4, 256, 0, stream>>>(pagg, cnt, out, sem, gam, bet);
}